// Round 4
// baseline (2614.454 us; speedup 1.0000x reference)
//
#include <hip/hip_runtime.h>
#include <hip/hip_bf16.h>
#include <cmath>

// GMM E-step: N=131072, K=64, D=256.
// Round 4: round-2 structure (proven 0-conflict B path, 16x16x32 MFMA)
// with A-fragments hoisted to registers (128 VGPR/lane), loaded coalesced
// from a fragment-layout prep image. LDS = B dbuf only (66KB) -> 2
// blocks/CU, 4 waves/SIMD; per-substep LDS traffic halved.

typedef unsigned short ushort_t;
typedef __attribute__((ext_vector_type(4))) float f32x4;
typedef __attribute__((ext_vector_type(8))) short bf16x8;

constexpr int N_ = 131072;
constexpr int K_ = 64;
constexpr int D_ = 256;
constexpr int BM = 128;                 // rows per block
constexpr int NBLK = N_ / BM;           // 1024 blocks
constexpr int BK = 64;                  // contraction substep
constexpr int NSUB = (K_ * D_) / BK;    // 256 total substeps

// ---------- helpers ----------
__device__ __forceinline__ ushort_t f2bf(float v) {
  unsigned u = __float_as_uint(v);
  u += 0x7FFFu + ((u >> 16) & 1u);  // RNE
  return (ushort_t)(u >> 16);
}

__device__ __forceinline__ void gld16(const ushort_t* g, ushort_t* l) {
  __builtin_amdgcn_global_load_lds(
      (const __attribute__((address_space(1))) unsigned int*)g,
      (__attribute__((address_space(3))) unsigned int*)l, 16, 0, 0);
}

// ---------- prep: X fp32 -> bf16 per-wave A-fragment image ----------
// e = (((T*2+wr)*4 + m)*8 + kc)*512 + lane*8 + j  holds
//   bf16( X[T*128 + wr*64 + m*16 + (lane&15)][kc*32 + (lane>>4)*8 + j] )
// (A-operand of mfma_f32_16x16x32_bf16: row=lane&15, k=(lane>>4)*8+j)
__global__ void prep_x(const float* __restrict__ X, ushort_t* __restrict__ Xb) {
  for (int e = blockIdx.x * blockDim.x + threadIdx.x; e < N_ * D_;
       e += gridDim.x * blockDim.x) {
    int j = e & 7;
    int lane = (e >> 3) & 63;
    int kc = (e >> 9) & 7;
    int m = (e >> 12) & 3;
    int wr = (e >> 14) & 1;
    int T = e >> 15;
    int row = T * 128 + wr * 64 + m * 16 + (lane & 15);
    int col = kc * 32 + (lane >> 4) * 8 + j;
    Xb[e] = f2bf(X[(size_t)row * D_ + col]);
  }
}

// ---------- prep: P fp32 -> bf16 transposed+swizzled image ----------
// image element e = ((k*4+s)*256 + j)*64 + iq  holds
//   bf16( P[k][s*64 + (iq ^ ((j&7)<<3))][j] )
__global__ void prep_p(const float* __restrict__ P, ushort_t* __restrict__ Pb) {
  for (int e = blockIdx.x * blockDim.x + threadIdx.x; e < K_ * D_ * D_;
       e += gridDim.x * blockDim.x) {
    int iq = e & 63;
    int j = (e >> 6) & 255;
    int s = (e >> 14) & 3;
    int k = e >> 16;
    int il = iq ^ ((j & 7) << 3);
    Pb[e] = f2bf(P[((size_t)k * D_ + s * 64 + il) * D_ + j]);
  }
}

// ---------- prep: t[k][j] = sum_i mu[k][i]*P[k][i][j];  C[k] ----------
__global__ void prep_t(const float* __restrict__ P, const float* __restrict__ mu,
                       const float* __restrict__ w, float* __restrict__ t,
                       float* __restrict__ C) {
  int k = blockIdx.x, j = threadIdx.x;
  const float* Pk = P + (size_t)k * D_ * D_;
  const float* muk = mu + (size_t)k * D_;
  float acc = 0.f;
  for (int i = 0; i < D_; ++i) acc += muk[i] * Pk[(size_t)i * D_ + j];
  t[k * D_ + j] = acc;
  __shared__ float red[D_];
  red[j] = logf(Pk[(size_t)j * D_ + j]);
  __syncthreads();
  for (int s = 128; s > 0; s >>= 1) {
    if (j < s) red[j] += red[j + s];
    __syncthreads();
  }
  if (j == 0)
    C[k] = red[0] + logf(w[k]) - 0.5f * (float)D_ * logf(2.0f * (float)M_PI);
}

// ---------- main: A-in-registers fused GEMM + per-k sq-reduce ----------
__global__ __launch_bounds__(512, 4) void gmm_main(
    const ushort_t* __restrict__ Xb, const ushort_t* __restrict__ Pb,
    const float* __restrict__ tvec, const float* __restrict__ Cvec,
    float* __restrict__ wlp /* [N][K] */) {
  __shared__ __align__(16) ushort_t Bl[2][256 * 64];  // 64 KiB, P_k dbuf
  __shared__ float sqred[BM][4];

  const int tid = threadIdx.x;
  const int T = blockIdx.x;

  const int wid = tid >> 6, lane = tid & 63;
  const int wr = wid >> 2, wc = wid & 3;  // wave tile: 64 rows x 64 cols
  const int lc = lane & 15, lg = lane >> 4;
  const int swzl = (lc & 7) << 3;  // LDS XOR swizzle (ushort units)

  // ---- load A fragments for this wave: 32 x bf16x8 = 128 VGPRs ----
  // frag f = m*8 + kc; coalesced: lane reads 16B at f*1KB + lane*16B
  const ushort_t* Ag = Xb + (size_t)(T * 2 + wr) * 16384;
  bf16x8 Areg[32];
#pragma unroll
  for (int f = 0; f < 32; ++f)
    Areg[f] = *(const bf16x8*)&Ag[f * 512 + lane * 8];

  auto STAGE_B = [&](int buf, int step) {
    const ushort_t* gb = Pb + (size_t)step * (256 * 64);
#pragma unroll
    for (int it = 0; it < 4; ++it) {
      int off = (it * 512 + tid) * 8;  // 16B chunks, linear image
      gld16(gb + off, &Bl[buf][off]);
    }
  };

  STAGE_B(0, 0);
  asm volatile("s_waitcnt vmcnt(0)" ::: "memory");
  __syncthreads();

#pragma unroll 1
  for (int k = 0; k < K_; ++k) {
    // prefetch epilogue constants (consumed ~4000 cyc later)
    float tv[4];
#pragma unroll
    for (int n = 0; n < 4; ++n) tv[n] = tvec[k * D_ + wc * 64 + n * 16 + lc];
    const float Ck = Cvec[k];

    f32x4 acc[4][4];
#pragma unroll
    for (int m = 0; m < 4; ++m)
#pragma unroll
      for (int n = 0; n < 4; ++n) acc[m][n] = (f32x4){0.f, 0.f, 0.f, 0.f};

#pragma unroll
    for (int s = 0; s < 4; ++s) {
      const int buf = s & 1;
      const int g1 = k * 4 + s + 1;
      if (g1 < NSUB) STAGE_B(buf ^ 1, g1);
#pragma unroll
      for (int ki = 0; ki < 2; ++ki) {
        const int cidx = (ki * 32 + lg * 8) ^ swzl;
        bf16x8 bb[4];
#pragma unroll
        for (int n = 0; n < 4; ++n)
          bb[n] = *(const bf16x8*)&Bl[buf][(wc * 64 + n * 16 + lc) * 64 + cidx];
#pragma unroll
        for (int m = 0; m < 4; ++m)
#pragma unroll
          for (int n = 0; n < 4; ++n)
            acc[m][n] = __builtin_amdgcn_mfma_f32_16x16x32_bf16(
                Areg[m * 8 + s * 2 + ki], bb[n], acc[m][n], 0, 0, 0);
      }
      asm volatile("s_waitcnt vmcnt(0)" ::: "memory");
      __syncthreads();
    }

    // epilogue for component k: sq = sum_j (z - t_j)^2, wave-local + LDS
#pragma unroll
    for (int m = 0; m < 4; ++m) {
#pragma unroll
      for (int r = 0; r < 4; ++r) {
        float sfl = 0.f;
#pragma unroll
        for (int n = 0; n < 4; ++n) {
          float d = acc[m][n][r] - tv[n];
          sfl += d * d;
        }
        sfl += __shfl_xor(sfl, 1, 64);
        sfl += __shfl_xor(sfl, 2, 64);
        sfl += __shfl_xor(sfl, 4, 64);
        sfl += __shfl_xor(sfl, 8, 64);
        if (lc == 0) sqred[wr * 64 + m * 16 + lg * 4 + r][wc] = sfl;
      }
    }
    __syncthreads();
    if (tid < BM) {
      float sq = sqred[tid][0] + sqred[tid][1] + sqred[tid][2] + sqred[tid][3];
      wlp[(size_t)(T * BM + tid) * K_ + k] = -0.5f * sq + Ck;
    }
    // next sqred write is >= 4 substep barriers away -> no extra barrier
  }
}

// ---------- LSE over k + write log_resp, per-block partial sums ----------
__global__ void lse_k(float* __restrict__ out, float* __restrict__ partial) {
  const int row = blockIdx.x * 256 + threadIdx.x;
  float* w = out + 1 + (size_t)row * K_;
  float v[K_];
  float mx = -1e30f;
#pragma unroll
  for (int j = 0; j < K_; ++j) {
    v[j] = w[j];
    mx = fmaxf(mx, v[j]);
  }
  float ssum = 0.f;
#pragma unroll
  for (int j = 0; j < K_; ++j) ssum += expf(v[j] - mx);
  float l = mx + logf(ssum);
#pragma unroll
  for (int j = 0; j < K_; ++j) w[j] = v[j] - l;
  __shared__ float red[256];
  red[threadIdx.x] = l;
  __syncthreads();
  for (int s = 128; s > 0; s >>= 1) {
    if (threadIdx.x < s) red[threadIdx.x] += red[threadIdx.x + s];
    __syncthreads();
  }
  if (threadIdx.x == 0) partial[blockIdx.x] = red[0];
}

__global__ void final_red(const float* __restrict__ partial,
                          float* __restrict__ out) {
  __shared__ float red[512];
  red[threadIdx.x] = partial[threadIdx.x];
  __syncthreads();
  for (int s = 256; s > 0; s >>= 1) {
    if (threadIdx.x < s) red[threadIdx.x] += red[threadIdx.x + s];
    __syncthreads();
  }
  if (threadIdx.x == 0) out[0] = red[0] * (1.0f / (float)N_);
}

extern "C" void kernel_launch(void* const* d_in, const int* in_sizes, int n_in,
                              void* d_out, int out_size, void* d_ws,
                              size_t ws_size, hipStream_t stream) {
  const float* X = (const float*)d_in[0];
  const float* w = (const float*)d_in[1];
  const float* mu = (const float*)d_in[2];
  const float* P = (const float*)d_in[3];
  float* out = (float*)d_out;
  char* ws = (char*)d_ws;

  // ws layout (bytes)
  ushort_t* Xb = (ushort_t*)ws;                         // 67,108,864
  ushort_t* Pb = (ushort_t*)(ws + 67108864);            // 8,388,608
  float* t = (float*)(ws + 75497472);                   // 65,536
  float* C = (float*)(ws + 75563008);                   // 256
  float* partial = (float*)(ws + 75563264);             // 2,048

  prep_x<<<2048, 256, 0, stream>>>(X, Xb);
  prep_p<<<2048, 256, 0, stream>>>(P, Pb);
  prep_t<<<K_, 256, 0, stream>>>(P, mu, w, t, C);
  gmm_main<<<NBLK, 512, 0, stream>>>(Xb, Pb, t, C, out + 1);
  lse_k<<<N_ / 256, 256, 0, stream>>>(out, partial);
  final_red<<<1, 512, 0, stream>>>(partial, out);
}

// Round 5
// 1627.934 us; speedup vs baseline: 1.6060x; 1.6060x over previous
//
#include <hip/hip_runtime.h>
#include <hip/hip_bf16.h>
#include <cmath>

// GMM E-step: N=131072, K=64, D=256.
// Round 5: barrier-free main loop. A staged once to LDS (fragment-linear,
// conflict-free, read-only). B streamed global->registers from a
// fragment image (L2/L3-hot), ping-pong on unrolled s-parity. Only one
// barrier per component (sqred reduce, parity double-buffered).

typedef unsigned short ushort_t;
typedef __attribute__((ext_vector_type(4))) float f32x4;
typedef __attribute__((ext_vector_type(8))) short bf16x8;

constexpr int N_ = 131072;
constexpr int K_ = 64;
constexpr int D_ = 256;
constexpr int BM = 128;                 // rows per block
constexpr int NBLK = N_ / BM;           // 1024 blocks
constexpr int NSUB = 256;               // total 64-k substeps (K*D/64)

// ---------- helpers ----------
__device__ __forceinline__ ushort_t f2bf(float v) {
  unsigned u = __float_as_uint(v);
  u += 0x7FFFu + ((u >> 16) & 1u);  // RNE
  return (ushort_t)(u >> 16);
}

__device__ __forceinline__ void gld16(const ushort_t* g, ushort_t* l) {
  __builtin_amdgcn_global_load_lds(
      (const __attribute__((address_space(1))) unsigned int*)g,
      (__attribute__((address_space(3))) unsigned int*)l, 16, 0, 0);
}

// ---------- prep: X fp32 -> bf16 A-fragment image ----------
// e = ((T*8 + mm)*8 + kc)*512 + lane*8 + j  holds
//   bf16( X[T*128 + mm*16 + (lane&15)][kc*32 + (lane>>4)*8 + j] )
// (A-operand of mfma_f32_16x16x32_bf16: row=lane&15, k=(lane>>4)*8+j)
__global__ void prep_x(const float* __restrict__ X, ushort_t* __restrict__ Xb) {
  for (int e = blockIdx.x * blockDim.x + threadIdx.x; e < N_ * D_;
       e += gridDim.x * blockDim.x) {
    int j = e & 7;
    int lane = (e >> 3) & 63;
    int kc = (e >> 9) & 7;
    int mm = (e >> 12) & 7;
    int T = e >> 15;
    int row = T * 128 + mm * 16 + (lane & 15);
    int col = kc * 32 + (lane >> 4) * 8 + j;
    Xb[e] = f2bf(X[(size_t)row * D_ + col]);
  }
}

// ---------- prep: P fp32 -> bf16 B-fragment image ----------
// fr = ((g*4 + wc)*8 + ki*4 + n), g = k*4+s;  e = fr*512 + lane*8 + j holds
//   bf16( P[k][s*64 + ki*32 + (lane>>4)*8 + j][wc*64 + n*16 + (lane&15)] )
// (B-operand of mfma_f32_16x16x32_bf16: col=lane&15, k=(lane>>4)*8+j)
__global__ void prep_p(const float* __restrict__ P, ushort_t* __restrict__ Pb) {
  for (int e = blockIdx.x * blockDim.x + threadIdx.x; e < K_ * D_ * D_;
       e += gridDim.x * blockDim.x) {
    int j = e & 7;
    int lane = (e >> 3) & 63;
    int n = (e >> 9) & 3;
    int ki = (e >> 11) & 1;
    int wc = (e >> 12) & 3;
    int s = (e >> 14) & 3;
    int k = e >> 16;
    int row_p = s * 64 + ki * 32 + (lane >> 4) * 8 + j;
    int col_p = wc * 64 + n * 16 + (lane & 15);
    Pb[e] = f2bf(P[((size_t)k * D_ + row_p) * D_ + col_p]);
  }
}

// ---------- prep: t[k][j] = sum_i mu[k][i]*P[k][i][j];  C[k] ----------
__global__ void prep_t(const float* __restrict__ P, const float* __restrict__ mu,
                       const float* __restrict__ w, float* __restrict__ t,
                       float* __restrict__ C) {
  int k = blockIdx.x, j = threadIdx.x;
  const float* Pk = P + (size_t)k * D_ * D_;
  const float* muk = mu + (size_t)k * D_;
  float acc = 0.f;
  for (int i = 0; i < D_; ++i) acc += muk[i] * Pk[(size_t)i * D_ + j];
  t[k * D_ + j] = acc;
  __shared__ float red[D_];
  red[j] = logf(Pk[(size_t)j * D_ + j]);
  __syncthreads();
  for (int s = 128; s > 0; s >>= 1) {
    if (j < s) red[j] += red[j + s];
    __syncthreads();
  }
  if (j == 0)
    C[k] = red[0] + logf(w[k]) - 0.5f * (float)D_ * logf(2.0f * (float)M_PI);
}

// ---------- main: A in LDS (read-only), B global->reg, 1 barrier/k ----------
__global__ __launch_bounds__(512, 2) void gmm_main(
    const ushort_t* __restrict__ Xb, const ushort_t* __restrict__ Pb,
    const float* __restrict__ tvec, const float* __restrict__ Cvec,
    float* __restrict__ wlp /* [N][K] */) {
  __shared__ __align__(16) ushort_t Al[32768];     // 64 KiB A fragments
  __shared__ float sqred[2][BM][4];                // parity dbuf, 4 KiB

  const int tid = threadIdx.x;
  const int T = blockIdx.x;

  const int wid = tid >> 6, lane = tid & 63;
  const int wr = wid >> 2, wc = wid & 3;  // wave tile: 64 rows x 64 cols
  const int lc = lane & 15, lg = lane >> 4;

  // ---- stage A once: 64 KiB, fragment-linear (dest == linear order) ----
  const ushort_t* Ag = Xb + (size_t)T * 32768;
#pragma unroll
  for (int it = 0; it < 8; ++it) {
    int off = (it * 512 + tid) * 8;
    gld16(Ag + off, &Al[off]);
  }
  asm volatile("s_waitcnt vmcnt(0)" ::: "memory");
  __syncthreads();

  // ---- B register pipeline: B[parity][8 frags], parity = s&1 (static) ----
  bf16x8 B[2][8];
  {
    const ushort_t* gb = Pb + (size_t)wc * 4096 + lane * 8;  // g=0
#pragma unroll
    for (int f = 0; f < 8; ++f) B[0][f] = *(const bf16x8*)(gb + f * 512);
  }

#pragma unroll 1
  for (int k = 0; k < K_; ++k) {
    float tv[4];
#pragma unroll
    for (int n = 0; n < 4; ++n) tv[n] = tvec[k * D_ + wc * 64 + n * 16 + lc];
    const float Ck = Cvec[k];

    f32x4 acc[4][4];
#pragma unroll
    for (int m = 0; m < 4; ++m)
#pragma unroll
      for (int n = 0; n < 4; ++n) acc[m][n] = (f32x4){0.f, 0.f, 0.f, 0.f};

#pragma unroll
    for (int s = 0; s < 4; ++s) {
      const int cur = s & 1;
      const int g1 = k * 4 + s + 1;
      if (g1 < NSUB) {  // prefetch next substep's B frags into other parity
        const ushort_t* gb =
            Pb + (size_t)g1 * 16384 + (size_t)wc * 4096 + lane * 8;
#pragma unroll
        for (int f = 0; f < 8; ++f)
          B[cur ^ 1][f] = *(const bf16x8*)(gb + f * 512);
      }
#pragma unroll
      for (int ki = 0; ki < 2; ++ki) {
#pragma unroll
        for (int m = 0; m < 4; ++m) {
          const int f = (wr * 4 + m) * 8 + s * 2 + ki;
          bf16x8 a = *(const bf16x8*)&Al[f * 512 + lane * 8];
#pragma unroll
          for (int n = 0; n < 4; ++n)
            acc[m][n] = __builtin_amdgcn_mfma_f32_16x16x32_bf16(
                a, B[cur][ki * 4 + n], acc[m][n], 0, 0, 0);
        }
      }
    }

    // epilogue: sq over this wave's 64-col slice, parity-buffered reduce
    const int par = k & 1;
#pragma unroll
    for (int m = 0; m < 4; ++m) {
#pragma unroll
      for (int r = 0; r < 4; ++r) {
        float sfl = 0.f;
#pragma unroll
        for (int n = 0; n < 4; ++n) {
          float d = acc[m][n][r] - tv[n];
          sfl += d * d;
        }
        sfl += __shfl_xor(sfl, 1, 64);
        sfl += __shfl_xor(sfl, 2, 64);
        sfl += __shfl_xor(sfl, 4, 64);
        sfl += __shfl_xor(sfl, 8, 64);
        if (lc == 0) sqred[par][wr * 64 + m * 16 + lg * 4 + r][wc] = sfl;
      }
    }
    __syncthreads();  // the only barrier per component
    if (tid < BM) {
      float sq = sqred[par][tid][0] + sqred[par][tid][1] + sqred[par][tid][2] +
                 sqred[par][tid][3];
      wlp[(size_t)(T * BM + tid) * K_ + k] = -0.5f * sq + Ck;
    }
  }
}

// ---------- LSE over k + write log_resp, per-block partial sums ----------
__global__ void lse_k(float* __restrict__ out, float* __restrict__ partial) {
  const int row = blockIdx.x * 256 + threadIdx.x;
  float* w = out + 1 + (size_t)row * K_;
  float v[K_];
  float mx = -1e30f;
#pragma unroll
  for (int j = 0; j < K_; ++j) {
    v[j] = w[j];
    mx = fmaxf(mx, v[j]);
  }
  float ssum = 0.f;
#pragma unroll
  for (int j = 0; j < K_; ++j) ssum += expf(v[j] - mx);
  float l = mx + logf(ssum);
#pragma unroll
  for (int j = 0; j < K_; ++j) w[j] = v[j] - l;
  __shared__ float red[256];
  red[threadIdx.x] = l;
  __syncthreads();
  for (int s = 128; s > 0; s >>= 1) {
    if (threadIdx.x < s) red[threadIdx.x] += red[threadIdx.x + s];
    __syncthreads();
  }
  if (threadIdx.x == 0) partial[blockIdx.x] = red[0];
}

__global__ void final_red(const float* __restrict__ partial,
                          float* __restrict__ out) {
  __shared__ float red[512];
  red[threadIdx.x] = partial[threadIdx.x];
  __syncthreads();
  for (int s = 256; s > 0; s >>= 1) {
    if (threadIdx.x < s) red[threadIdx.x] += red[threadIdx.x + s];
    __syncthreads();
  }
  if (threadIdx.x == 0) out[0] = red[0] * (1.0f / (float)N_);
}

extern "C" void kernel_launch(void* const* d_in, const int* in_sizes, int n_in,
                              void* d_out, int out_size, void* d_ws,
                              size_t ws_size, hipStream_t stream) {
  const float* X = (const float*)d_in[0];
  const float* w = (const float*)d_in[1];
  const float* mu = (const float*)d_in[2];
  const float* P = (const float*)d_in[3];
  float* out = (float*)d_out;
  char* ws = (char*)d_ws;

  // ws layout (bytes)
  ushort_t* Xb = (ushort_t*)ws;                         // 67,108,864
  ushort_t* Pb = (ushort_t*)(ws + 67108864);            // 8,388,608
  float* t = (float*)(ws + 75497472);                   // 65,536
  float* C = (float*)(ws + 75563008);                   // 256
  float* partial = (float*)(ws + 75563264);             // 2,048

  prep_x<<<2048, 256, 0, stream>>>(X, Xb);
  prep_p<<<2048, 256, 0, stream>>>(P, Pb);
  prep_t<<<K_, 256, 0, stream>>>(P, mu, w, t, C);
  gmm_main<<<NBLK, 512, 0, stream>>>(Xb, Pb, t, C, out + 1);
  lse_k<<<N_ / 256, 256, 0, stream>>>(out, partial);
  final_red<<<1, 512, 0, stream>>>(partial, out);
}

// Round 7
// 1517.063 us; speedup vs baseline: 1.7234x; 1.0731x over previous
//
#include <hip/hip_runtime.h>
#include <hip/hip_bf16.h>
#include <cmath>

// GMM E-step: N=131072, K=64, D=256.
// Round 6 (resubmit after infra failure): round-5 structure + depth-3 B
// register pipeline (B[4][8], statically indexed), raw s_barrier +
// lgkmcnt-only at the per-k reduce (vmcnt never drained in the main
// loop), and per-k results buffered in LDS, flushed coalesced once.

typedef unsigned short ushort_t;
typedef __attribute__((ext_vector_type(4))) float f32x4;
typedef __attribute__((ext_vector_type(8))) short bf16x8;

constexpr int N_ = 131072;
constexpr int K_ = 64;
constexpr int D_ = 256;
constexpr int BM = 128;                 // rows per block
constexpr int NBLK = N_ / BM;           // 1024 blocks
constexpr int NSUB = 256;               // total 64-k substeps (K*D/64)

// ---------- helpers ----------
__device__ __forceinline__ ushort_t f2bf(float v) {
  unsigned u = __float_as_uint(v);
  u += 0x7FFFu + ((u >> 16) & 1u);  // RNE
  return (ushort_t)(u >> 16);
}

__device__ __forceinline__ void gld16(const ushort_t* g, ushort_t* l) {
  __builtin_amdgcn_global_load_lds(
      (const __attribute__((address_space(1))) unsigned int*)g,
      (__attribute__((address_space(3))) unsigned int*)l, 16, 0, 0);
}

// ---------- prep: X fp32 -> bf16 A-fragment image ----------
// e = ((T*8 + mm)*8 + kc)*512 + lane*8 + j  holds
//   bf16( X[T*128 + mm*16 + (lane&15)][kc*32 + (lane>>4)*8 + j] )
__global__ void prep_x(const float* __restrict__ X, ushort_t* __restrict__ Xb) {
  for (int e = blockIdx.x * blockDim.x + threadIdx.x; e < N_ * D_;
       e += gridDim.x * blockDim.x) {
    int j = e & 7;
    int lane = (e >> 3) & 63;
    int kc = (e >> 9) & 7;
    int mm = (e >> 12) & 7;
    int T = e >> 15;
    int row = T * 128 + mm * 16 + (lane & 15);
    int col = kc * 32 + (lane >> 4) * 8 + j;
    Xb[e] = f2bf(X[(size_t)row * D_ + col]);
  }
}

// ---------- prep: P fp32 -> bf16 B-fragment image ----------
// fr = ((g*4 + wc)*8 + ki*4 + n);  e = fr*512 + lane*8 + j holds
//   bf16( P[k][s*64 + ki*32 + (lane>>4)*8 + j][wc*64 + n*16 + (lane&15)] )
__global__ void prep_p(const float* __restrict__ P, ushort_t* __restrict__ Pb) {
  for (int e = blockIdx.x * blockDim.x + threadIdx.x; e < K_ * D_ * D_;
       e += gridDim.x * blockDim.x) {
    int j = e & 7;
    int lane = (e >> 3) & 63;
    int n = (e >> 9) & 3;
    int ki = (e >> 11) & 1;
    int wc = (e >> 12) & 3;
    int s = (e >> 14) & 3;
    int k = e >> 16;
    int row_p = s * 64 + ki * 32 + (lane >> 4) * 8 + j;
    int col_p = wc * 64 + n * 16 + (lane & 15);
    Pb[e] = f2bf(P[((size_t)k * D_ + row_p) * D_ + col_p]);
  }
}

// ---------- prep: t[k][j] = sum_i mu[k][i]*P[k][i][j];  C[k] ----------
__global__ void prep_t(const float* __restrict__ P, const float* __restrict__ mu,
                       const float* __restrict__ w, float* __restrict__ t,
                       float* __restrict__ C) {
  int k = blockIdx.x, j = threadIdx.x;
  const float* Pk = P + (size_t)k * D_ * D_;
  const float* muk = mu + (size_t)k * D_;
  float acc = 0.f;
  for (int i = 0; i < D_; ++i) acc += muk[i] * Pk[(size_t)i * D_ + j];
  t[k * D_ + j] = acc;
  __shared__ float red[D_];
  red[j] = logf(Pk[(size_t)j * D_ + j]);
  __syncthreads();
  for (int s = 128; s > 0; s >>= 1) {
    if (j < s) red[j] += red[j + s];
    __syncthreads();
  }
  if (j == 0)
    C[k] = red[0] + logf(w[k]) - 0.5f * (float)D_ * logf(2.0f * (float)M_PI);
}

// ---------- main: A in LDS, B global->reg depth-3 pipeline ----------
__global__ __launch_bounds__(512, 2) void gmm_main(
    const ushort_t* __restrict__ Xb, const ushort_t* __restrict__ Pb,
    const float* __restrict__ tvec, const float* __restrict__ Cvec,
    float* __restrict__ wlp /* [N][K] */) {
  __shared__ __align__(16) ushort_t Al[32768];     // 64 KiB A fragments
  __shared__ float sqred[2][BM][4];                // parity dbuf, 4 KiB
  __shared__ __align__(16) float wlpl[BM][K_];     // 32 KiB result buffer

  const int tid = threadIdx.x;
  const int T = blockIdx.x;

  const int wid = tid >> 6, lane = tid & 63;
  const int wr = wid >> 2, wc = wid & 3;  // wave tile: 64 rows x 64 cols
  const int lc = lane & 15, lg = lane >> 4;

  // ---- stage A once: 64 KiB, fragment-linear ----
  const ushort_t* Ag = Xb + (size_t)T * 32768;
#pragma unroll
  for (int it = 0; it < 8; ++it) {
    int off = (it * 512 + tid) * 8;
    gld16(Ag + off, &Al[off]);
  }
  asm volatile("s_waitcnt vmcnt(0)" ::: "memory");
  __builtin_amdgcn_s_barrier();

  // ---- B register pipeline: depth 3, 4 buffers, static indices ----
  bf16x8 B[4][8];
#pragma unroll
  for (int pg = 0; pg < 3; ++pg) {
    const ushort_t* gb = Pb + (size_t)pg * 16384 + (size_t)wc * 4096 + lane * 8;
#pragma unroll
    for (int f = 0; f < 8; ++f) B[pg][f] = *(const bf16x8*)(gb + f * 512);
  }

#pragma unroll 1
  for (int k = 0; k < K_; ++k) {
    float tv[4];
#pragma unroll
    for (int n = 0; n < 4; ++n) tv[n] = tvec[k * D_ + wc * 64 + n * 16 + lc];
    const float Ck = Cvec[k];

    f32x4 acc[4][4];
#pragma unroll
    for (int m = 0; m < 4; ++m)
#pragma unroll
      for (int n = 0; n < 4; ++n) acc[m][n] = (f32x4){0.f, 0.f, 0.f, 0.f};

#pragma unroll
    for (int s = 0; s < 4; ++s) {
      const int gp = k * 4 + s + 3;  // prefetch 3 substeps ahead
      if (gp < NSUB) {
        const ushort_t* gb =
            Pb + (size_t)gp * 16384 + (size_t)wc * 4096 + lane * 8;
#pragma unroll
        for (int f = 0; f < 8; ++f)
          B[(s + 3) & 3][f] = *(const bf16x8*)(gb + f * 512);
      }
#pragma unroll
      for (int ki = 0; ki < 2; ++ki) {
#pragma unroll
        for (int m = 0; m < 4; ++m) {
          const int fA = (wr * 4 + m) * 8 + s * 2 + ki;
          bf16x8 a = *(const bf16x8*)&Al[fA * 512 + lane * 8];
#pragma unroll
          for (int n = 0; n < 4; ++n)
            acc[m][n] = __builtin_amdgcn_mfma_f32_16x16x32_bf16(
                a, B[s][ki * 4 + n], acc[m][n], 0, 0, 0);
        }
      }
    }

    // epilogue: cross-lane sq reduce -> sqred (LDS only, no vmem)
    const int par = k & 1;
#pragma unroll
    for (int m = 0; m < 4; ++m) {
#pragma unroll
      for (int r = 0; r < 4; ++r) {
        float sfl = 0.f;
#pragma unroll
        for (int n = 0; n < 4; ++n) {
          float d = acc[m][n][r] - tv[n];
          sfl += d * d;
        }
        sfl += __shfl_xor(sfl, 1, 64);
        sfl += __shfl_xor(sfl, 2, 64);
        sfl += __shfl_xor(sfl, 4, 64);
        sfl += __shfl_xor(sfl, 8, 64);
        if (lc == 0) sqred[par][wr * 64 + m * 16 + lg * 4 + r][wc] = sfl;
      }
    }
    // raw barrier: drain DS only; B prefetches stay in flight across it
    asm volatile("s_waitcnt lgkmcnt(0)" ::: "memory");
    __builtin_amdgcn_s_barrier();
    if (tid < BM) {
      float sq = sqred[par][tid][0] + sqred[par][tid][1] + sqred[par][tid][2] +
                 sqred[par][tid][3];
      wlpl[tid][k] = -0.5f * sq + Ck;
    }
    // parity dbuf: next write to sqred[par] is after the k+1 barrier
  }

  // flush wlpl -> global, coalesced (32 KiB contiguous)
  asm volatile("s_waitcnt lgkmcnt(0)" ::: "memory");
  __builtin_amdgcn_s_barrier();
  float* dst = wlp + (size_t)T * BM * K_;
#pragma unroll
  for (int it = 0; it < 4; ++it) {
    int idx = it * 512 + tid;
    ((f32x4*)dst)[idx] = ((const f32x4*)wlpl)[idx];
  }
}

// ---------- LSE over k + write log_resp, per-block partial sums ----------
__global__ void lse_k(float* __restrict__ out, float* __restrict__ partial) {
  const int row = blockIdx.x * 256 + threadIdx.x;
  float* w = out + 1 + (size_t)row * K_;
  float v[K_];
  float mx = -1e30f;
#pragma unroll
  for (int j = 0; j < K_; ++j) {
    v[j] = w[j];
    mx = fmaxf(mx, v[j]);
  }
  float ssum = 0.f;
#pragma unroll
  for (int j = 0; j < K_; ++j) ssum += expf(v[j] - mx);
  float l = mx + logf(ssum);
#pragma unroll
  for (int j = 0; j < K_; ++j) w[j] = v[j] - l;
  __shared__ float red[256];
  red[threadIdx.x] = l;
  __syncthreads();
  for (int s = 128; s > 0; s >>= 1) {
    if (threadIdx.x < s) red[threadIdx.x] += red[threadIdx.x + s];
    __syncthreads();
  }
  if (threadIdx.x == 0) partial[blockIdx.x] = red[0];
}

__global__ void final_red(const float* __restrict__ partial,
                          float* __restrict__ out) {
  __shared__ float red[512];
  red[threadIdx.x] = partial[threadIdx.x];
  __syncthreads();
  for (int s = 256; s > 0; s >>= 1) {
    if (threadIdx.x < s) red[threadIdx.x] += red[threadIdx.x + s];
    __syncthreads();
  }
  if (threadIdx.x == 0) out[0] = red[0] * (1.0f / (float)N_);
}

extern "C" void kernel_launch(void* const* d_in, const int* in_sizes, int n_in,
                              void* d_out, int out_size, void* d_ws,
                              size_t ws_size, hipStream_t stream) {
  const float* X = (const float*)d_in[0];
  const float* w = (const float*)d_in[1];
  const float* mu = (const float*)d_in[2];
  const float* P = (const float*)d_in[3];
  float* out = (float*)d_out;
  char* ws = (char*)d_ws;

  // ws layout (bytes)
  ushort_t* Xb = (ushort_t*)ws;                         // 67,108,864
  ushort_t* Pb = (ushort_t*)(ws + 67108864);            // 8,388,608
  float* t = (float*)(ws + 75497472);                   // 65,536
  float* C = (float*)(ws + 75563008);                   // 256
  float* partial = (float*)(ws + 75563264);             // 2,048

  prep_x<<<2048, 256, 0, stream>>>(X, Xb);
  prep_p<<<2048, 256, 0, stream>>>(P, Pb);
  prep_t<<<K_, 256, 0, stream>>>(P, mu, w, t, C);
  gmm_main<<<NBLK, 512, 0, stream>>>(Xb, Pb, t, C, out + 1);
  lse_k<<<N_ / 256, 256, 0, stream>>>(out, partial);
  final_red<<<1, 512, 0, stream>>>(partial, out);
}